// Round 13
// baseline (630.977 us; speedup 1.0000x reference)
//
#include <hip/hip_runtime.h>
#include <hip/hip_bf16.h>

typedef _Float16 f16;
typedef _Float16 f16x8 __attribute__((ext_vector_type(8)));
typedef float f32x4 __attribute__((ext_vector_type(4)));

#define NBATCH 128
#define NTIME  128
#define NKIN   512
#define NUNITS 512
#define NGATE  2048

// per stream: 8 groups x 8 rows; 32 slots x 16 unit-cols (64 gate-cols)
#define GROWS  8
#define HSZ    (NBATCH * NUNITS)   // one h slot (f16 elems), shared by both streams
#define POISON 0x7C00u             // f16 +inf: impossible as h = o*tanh(c)

static __device__ __forceinline__ float sigmoidf_(float x) {
    return 1.0f / (1.0f + __expf(-x));
}
static __device__ __forceinline__ float tanhf_(float x) {
    float t = __expf(-2.0f * fabsf(x));
    float r = (1.0f - t) / (1.0f + t);
    return copysignf(r, x);
}

static __device__ __forceinline__ f16x8 pack8(float4 a, float4 b) {
    f16x8 r;
    r[0] = (f16)a.x; r[1] = (f16)a.y; r[2] = (f16)a.z; r[3] = (f16)a.w;
    r[4] = (f16)b.x; r[5] = (f16)b.y; r[6] = (f16)b.z; r[7] = (f16)b.w;
    return r;
}

// ---- MALL-coherent (sc0 sc1) ops ----
static __device__ __forceinline__ void store_u16_sys(void* p, unsigned short v) {
    asm volatile("global_store_short %0, %1, off sc0 sc1" :: "v"(p), "v"(v) : "memory");
}
static __device__ __forceinline__ void store_16B_sys(void* p, f32x4 v) {
    asm volatile("global_store_dwordx4 %0, %1, off sc0 sc1" :: "v"(p), "v"(v) : "memory");
}
// synchronous paired load (re-poll fallback path)
static __device__ __forceinline__ void load2x16_sys(const void* p0, const void* p1,
                                                    f32x4* a, f32x4* b) {
    asm volatile("global_load_dwordx4 %0, %2, off sc0 sc1\n\t"
                 "global_load_dwordx4 %1, %3, off sc0 sc1\n\t"
                 "s_waitcnt vmcnt(0)"
                 : "=&v"(*a), "=&v"(*b) : "v"(p0), "v"(p1) : "memory");
}
// ASYNC probe issue (no wait) — RTT hides under the MFMA section
static __device__ __forceinline__ void probe2x16_sys(const void* p0, const void* p1,
                                                     f32x4* a, f32x4* b) {
    asm volatile("global_load_dwordx4 %0, %2, off sc0 sc1\n\t"
                 "global_load_dwordx4 %1, %3, off sc0 sc1"
                 : "=&v"(*a), "=&v"(*b) : "v"(p0), "v"(p1) : "memory");
}
// ASYNC xz prefetch: 4 scalar f16 loads (plain cached), waited 1 phase later
static __device__ __forceinline__ void issue_px(const f16* base, unsigned* r0_, unsigned* r1_,
                                                unsigned* r2_, unsigned* r3_) {
    asm volatile("global_load_ushort %0, %4, off\n\t"
                 "global_load_ushort %1, %5, off\n\t"
                 "global_load_ushort %2, %6, off\n\t"
                 "global_load_ushort %3, %7, off"
                 : "=&v"(*r0_), "=&v"(*r1_), "=&v"(*r2_), "=&v"(*r3_)
                 : "v"(base), "v"(base + NGATE), "v"(base + 2 * NGATE), "v"(base + 3 * NGATE)
                 : "memory");
}
// single drain point: ties probes AND px payloads so no consumer can hoist above it
static __device__ __forceinline__ void wait_vm0(f32x4* a, f32x4* b, unsigned* p0, unsigned* p1,
                                                unsigned* p2, unsigned* p3) {
    asm volatile("s_waitcnt vmcnt(0)"
                 : "+v"(*a), "+v"(*b), "+v"(*p0), "+v"(*p1), "+v"(*p2), "+v"(*p3)
                 :: "memory");
}
static __device__ __forceinline__ float f16bits_to_f32(unsigned u) {
    union { unsigned short s; f16 h; } cv; cv.s = (unsigned short)(u & 0xFFFFu);
    return (float)cv.h;
}

// true if no f16 half of the 16B chunk equals the poison pattern
static __device__ __forceinline__ int chunk_clean(f32x4 v) {
#pragma unroll
    for (int i = 0; i < 4; ++i) {
        unsigned u = __float_as_uint(v[i]);
        if ((u & 0xFFFFu) == POISON || (u >> 16) == POISON) return 0;
    }
    return 1;
}

// ---------------- poison init ----------------
__global__ __launch_bounds__(256)
void k_poison(f16* __restrict__ hsl) {
    f32x4 v;
    const float pf = __uint_as_float((POISON << 16) | POISON);
#pragma unroll
    for (int i = 0; i < 4; ++i) v[i] = pf;
    const size_t i = ((size_t)blockIdx.x * 256 + threadIdx.x) * 8;
    if (i < (size_t)3 * HSZ) *(f32x4*)(hsl + i) = v;
}

// ---------------- transpose: f32 in[512][2048] -> f16 out[2048][512] ----------------
__global__ __launch_bounds__(256)
void k_transpose(const float* __restrict__ in, f16* __restrict__ out) {
    __shared__ f16 tile[64][72];
    const int c0 = blockIdx.x * 64;
    const int r0 = blockIdx.y * 64;
    const int tid = threadIdx.x;
    {
        const int lr = tid >> 2;
        const int lc = (tid & 3) << 4;
        const float* src = in + (size_t)(r0 + lr) * NGATE + c0 + lc;
        float4 v0 = ((const float4*)src)[0];
        float4 v1 = ((const float4*)src)[1];
        float4 v2 = ((const float4*)src)[2];
        float4 v3 = ((const float4*)src)[3];
        *(f16x8*)&tile[lr][lc]     = pack8(v0, v1);
        *(f16x8*)&tile[lr][lc + 8] = pack8(v2, v3);
    }
    __syncthreads();
    {
        const int lc = tid >> 2;
        const int lr = (tid & 3) << 4;
        f16x8 a, b;
#pragma unroll
        for (int i = 0; i < 8; ++i) a[i] = tile[lr + i][lc];
#pragma unroll
        for (int i = 0; i < 8; ++i) b[i] = tile[lr + 8 + i][lc];
        f16* dst = out + (size_t)(c0 + lc) * NKIN + r0 + lr;
        *(f16x8*)dst       = a;
        *(f16x8*)(dst + 8) = b;
    }
}

// ---------------- projection ----------------
__global__ __launch_bounds__(256)
void k_proj(const float* __restrict__ x, const f16* __restrict__ Wt,
            const float* __restrict__ bias, f16* __restrict__ xz) {
    __shared__ f16 As[128][40];
    __shared__ f16 Bs[128][40];
    const int bid = blockIdx.y * gridDim.x + blockIdx.x;
    const int swz = (bid & 7) * 256 + (bid >> 3);
    const int nb = swz & 15;
    const int tb = swz >> 4;
    const int n0 = nb * 128;
    const int tid  = threadIdx.x;
    const int lane = tid & 63;
    const int wid  = tid >> 6;
    const int wm = (wid >> 1) * 64;
    const int wn = (wid & 1) * 64;
    const int lm = lane & 15;
    const int lg = lane >> 4;

    f32x4 acc[4][4];
#pragma unroll
    for (int mi = 0; mi < 4; ++mi)
#pragma unroll
        for (int ni = 0; ni < 4; ++ni)
#pragma unroll
            for (int i = 0; i < 4; ++i) acc[mi][ni][i] = 0.0f;

    for (int kt = 0; kt < NKIN; kt += 32) {
        {
            const int brow = tid >> 1;
            const int kq   = (tid & 1) << 4;
            const float* src = x + ((size_t)brow * NTIME + tb) * NKIN + kt + kq;
            float4 v0 = ((const float4*)src)[0];
            float4 v1 = ((const float4*)src)[1];
            float4 v2 = ((const float4*)src)[2];
            float4 v3 = ((const float4*)src)[3];
            *(f16x8*)&As[brow][kq]     = pack8(v0, v1);
            *(f16x8*)&As[brow][kq + 8] = pack8(v2, v3);
        }
        {
            const int nrow = tid >> 1;
            const int kq   = (tid & 1) << 4;
            const f16* src = Wt + (size_t)(n0 + nrow) * NKIN + kt + kq;
            *(f16x8*)&Bs[nrow][kq]     = *(const f16x8*)src;
            *(f16x8*)&Bs[nrow][kq + 8] = *(const f16x8*)(src + 8);
        }
        __syncthreads();
        f16x8 a[4], b[4];
#pragma unroll
        for (int mi = 0; mi < 4; ++mi)
            a[mi] = *(const f16x8*)&As[wm + mi * 16 + lm][lg * 8];
#pragma unroll
        for (int ni = 0; ni < 4; ++ni)
            b[ni] = *(const f16x8*)&Bs[wn + ni * 16 + lm][lg * 8];
#pragma unroll
        for (int mi = 0; mi < 4; ++mi)
#pragma unroll
            for (int ni = 0; ni < 4; ++ni)
                acc[mi][ni] = __builtin_amdgcn_mfma_f32_16x16x32_f16(a[mi], b[ni], acc[mi][ni], 0, 0, 0);
        __syncthreads();
    }
#pragma unroll
    for (int mi = 0; mi < 4; ++mi) {
#pragma unroll
        for (int ni = 0; ni < 4; ++ni) {
            const int col = n0 + wn + ni * 16 + lm;
            const float bv = bias[col];
#pragma unroll
            for (int i = 0; i < 4; ++i) {
                const int brow = wm + mi * 16 + lg * 4 + i;
                xz[((size_t)tb * NBATCH + brow) * NGATE + col] = (f16)(acc[mi][ni][i] + bv);
            }
        }
    }
}

// ---------------- persistent LSTM: 2-stream + async probes (T14 split) ----------
// r12 structure (passed) + the probe loads issued at PHASE START (RTT hides under
// the MFMA) and waited at a single explicit vmcnt(0) per tail. ALL steady-state
// VMEM is inline asm (xz prefetch = async ushort loads, waited one phase later)
// so the compiler emits no vmcnt inside the MFMA sections. Sync fallback poll
// loop (r12-verbatim) preserves correctness if a probe arrives dirty.
__global__ __launch_bounds__(256, 1)
void k_lstm(const f16* __restrict__ xz, const f16* __restrict__ Ut,
            f16* __restrict__ hsl, float* __restrict__ out) {
    __shared__ f16 Us[64][512];      // 64 gate-cols x 512 k, XOR-swizzled (64KB)
    __shared__ f16 AsA[16][512];     // stream A h rows (8 valid + 8 zero) (16KB)
    __shared__ f16 AsB[16][512];     // stream B h rows (16KB)
    __shared__ float zs[4][GROWS][17];
    const int bid = blockIdx.x;
    const int grp  = bid & 7;
    const int slot = bid >> 3;       // 0..31
    const int r0A = grp * GROWS;
    const int r0B = 64 + grp * GROWS;
    const int u0 = slot * 16;
    const int tid  = threadIdx.x;
    const int lane = tid & 63;
    const int g    = tid >> 6;
    const int lm = lane & 15;
    const int lg = lane >> 4;

    // one-time: stage 64 U gate-cols into LDS, XOR-swizzled
#pragma unroll
    for (int i = 0; i < 16; ++i) {
        const int idx = tid + i * 256;
        const int c   = idx >> 6;
        const int ck  = idx & 63;
        const int gcol = (c >> 4) * NUNITS + u0 + (c & 15);
        f16x8 v = *(const f16x8*)(Ut + (size_t)gcol * NUNITS + ck * 8);
        *(f16x8*)&Us[c][(ck ^ (c & 7)) * 8] = v;
    }
    {
        f32x4 z = {0.f, 0.f, 0.f, 0.f};
        for (int i = tid; i < 16 * 64; i += 256) {
            *(f32x4*)&AsA[i >> 6][(i & 63) * 8] = z;
            *(f32x4*)&AsB[i >> 6][(i & 63) * 8] = z;
        }
    }

    const int srow = tid >> 4;       // state row 0..7 (tid<128)
    const int suu  = tid & 15;
    const int gidxA = (r0A + srow) * NUNITS + u0 + suu;
    const int gidxB = (r0B + srow) * NUNITS + u0 + suu;
    const int prow = tid >> 5;       // probe/stage row 0..7
    const int pc0  = tid & 31;       // probe/stage chunk
    float c_regA = 0.0f, c_regB = 0.0f;

    f32x4 pz;
    {
        const float pf = __uint_as_float((POISON << 16) | POISON);
#pragma unroll
        for (int i = 0; i < 4; ++i) pz[i] = pf;
    }

    // t=0 xz preload (synchronous C++, before the loop)
    float pxA[4] = {0.f, 0.f, 0.f, 0.f};
    float pxB[4] = {0.f, 0.f, 0.f, 0.f};
    if (lg < 2) {
        const f16* xa = xz + ((size_t)(r0A + lg * 4)) * NGATE + g * NUNITS + u0 + lm;
        const f16* xb = xz + ((size_t)(r0B + lg * 4)) * NGATE + g * NUNITS + u0 + lm;
#pragma unroll
        for (int i = 0; i < 4; ++i) {
            pxA[i] = (float)xa[(size_t)i * NGATE];
            pxB[i] = (float)xb[(size_t)i * NGATE];
        }
    }
    unsigned puA[4], puB[4];         // in-flight xz payloads (u16 in u32)
    f32x4 prA_a, prA_b;              // phase-A probes (stream B data)
    f32x4 prB_a, prB_b;              // phase-B probes (stream A data)
    __syncthreads();

    for (int t = 0; t < NTIME; ++t) {
        // =================== PHASE A (stream A, time t) ===================
        if (t > 0) {  // async probe: stream B's h[t-1] (stored 1 phase ago -> clean)
            const f16* src = hsl + (size_t)((t + 2) % 3) * HSZ + (size_t)(r0B + prow) * NUNITS;
            probe2x16_sys(src + pc0 * 8, src + (pc0 + 32) * 8, &prA_a, &prA_b);
        }
        {   // MFMA A (LDS-only section; probes in flight underneath)
            f32x4 a0, a1, a2, a3;
#pragma unroll
            for (int i = 0; i < 4; ++i) { a0[i] = pxA[i]; a1[i] = 0.f; a2[i] = 0.f; a3[i] = 0.f; }
#pragma unroll
            for (int ks = 0; ks < 16; ks += 4) {
                const int ca0 = (((ks + 0) * 4 + lg) ^ (lm & 7)) * 8;
                const int ca1 = (((ks + 1) * 4 + lg) ^ (lm & 7)) * 8;
                const int ca2 = (((ks + 2) * 4 + lg) ^ (lm & 7)) * 8;
                const int ca3 = (((ks + 3) * 4 + lg) ^ (lm & 7)) * 8;
                a0 = __builtin_amdgcn_mfma_f32_16x16x32_f16(*(const f16x8*)&AsA[lm][ca0],
                        *(const f16x8*)&Us[g * 16 + lm][ca0], a0, 0, 0, 0);
                a1 = __builtin_amdgcn_mfma_f32_16x16x32_f16(*(const f16x8*)&AsA[lm][ca1],
                        *(const f16x8*)&Us[g * 16 + lm][ca1], a1, 0, 0, 0);
                a2 = __builtin_amdgcn_mfma_f32_16x16x32_f16(*(const f16x8*)&AsA[lm][ca2],
                        *(const f16x8*)&Us[g * 16 + lm][ca2], a2, 0, 0, 0);
                a3 = __builtin_amdgcn_mfma_f32_16x16x32_f16(*(const f16x8*)&AsA[lm][ca3],
                        *(const f16x8*)&Us[g * 16 + lm][ca3], a3, 0, 0, 0);
            }
            f32x4 acc = (a0 + a1) + (a2 + a3);
            if (lg < 2) {
#pragma unroll
                for (int i = 0; i < 4; ++i) zs[g][lg * 4 + i][lm] = acc[i];
            }
        }
        __syncthreads();
        // ---- tail A ----
        if (t > 0) {
            wait_vm0(&prA_a, &prA_b, &puB[0], &puB[1], &puB[2], &puB[3]);
            // pxB(t) was issued in phase B(t-1) tail; now guaranteed -> convert
            if (lg < 2) {
#pragma unroll
                for (int i = 0; i < 4; ++i) pxB[i] = f16bits_to_f32(puB[i]);
            }
            if (!(chunk_clean(prA_a) && chunk_clean(prA_b))) {   // fallback poll
                const f16* src = hsl + (size_t)((t + 2) % 3) * HSZ
                               + (size_t)(r0B + prow) * NUNITS;
                for (int spin = 0; spin < 65536; ++spin) {
                    load2x16_sys(src + pc0 * 8, src + (pc0 + 32) * 8, &prA_a, &prA_b);
                    if (chunk_clean(prA_a) && chunk_clean(prA_b)) break;
                }
            }
            *(f32x4*)&AsB[prow][(pc0 ^ (prow & 7)) * 8]        = prA_a;
            *(f32x4*)&AsB[prow][((pc0 + 32) ^ (prow & 7)) * 8] = prA_b;
            if (tid < 16) {   // poison B-rows of slot (t+1)%3
                f16* ps = hsl + (size_t)((t + 1) % 3) * HSZ
                              + (size_t)(r0B + (tid >> 1)) * NUNITS + u0 + (tid & 1) * 8;
                store_16B_sys(ps, pz);
            }
        }
        // state A (fire-and-forget store AFTER the wait -> never waited on)
        if (tid < 128) {
            const float zi = zs[0][srow][suu];
            const float zf = zs[1][srow][suu];
            const float zg_ = zs[2][srow][suu];
            const float zo = zs[3][srow][suu];
            const float iv = sigmoidf_(zi);
            const float fv = sigmoidf_(zf);
            const float gv = tanhf_(zg_);
            const float ov = sigmoidf_(zo);
            c_regA = fv * c_regA + iv * gv;
            const float hn = ov * tanhf_(c_regA);
            if (t == NTIME - 1) {
                out[gidxA]          = hn;
                out[65536 + gidxA]  = hn;
                out[131072 + gidxA] = c_regA;
            } else {
                union { f16 h; unsigned short u; } cv; cv.h = (f16)hn;
                store_u16_sys(hsl + (size_t)(t % 3) * HSZ + gidxA, cv.u);
            }
        }
        // async xz prefetch pxA(t+1) — guaranteed by phase B(t) tail's wait
        if (t + 1 < NTIME && lg < 2) {
            issue_px(xz + ((size_t)(t + 1) * NBATCH + r0A + lg * 4) * NGATE
                        + g * NUNITS + u0 + lm, &puA[0], &puA[1], &puA[2], &puA[3]);
        }
        __syncthreads();

        // =================== PHASE B (stream B, time t) ===================
        if (t + 1 < NTIME) {  // async probe: stream A's h[t] (stored in tail A)
            const f16* src = hsl + (size_t)(t % 3) * HSZ + (size_t)(r0A + prow) * NUNITS;
            probe2x16_sys(src + pc0 * 8, src + (pc0 + 32) * 8, &prB_a, &prB_b);
        }
        {   // MFMA B
            f32x4 a0, a1, a2, a3;
#pragma unroll
            for (int i = 0; i < 4; ++i) { a0[i] = pxB[i]; a1[i] = 0.f; a2[i] = 0.f; a3[i] = 0.f; }
#pragma unroll
            for (int ks = 0; ks < 16; ks += 4) {
                const int ca0 = (((ks + 0) * 4 + lg) ^ (lm & 7)) * 8;
                const int ca1 = (((ks + 1) * 4 + lg) ^ (lm & 7)) * 8;
                const int ca2 = (((ks + 2) * 4 + lg) ^ (lm & 7)) * 8;
                const int ca3 = (((ks + 3) * 4 + lg) ^ (lm & 7)) * 8;
                a0 = __builtin_amdgcn_mfma_f32_16x16x32_f16(*(const f16x8*)&AsB[lm][ca0],
                        *(const f16x8*)&Us[g * 16 + lm][ca0], a0, 0, 0, 0);
                a1 = __builtin_amdgcn_mfma_f32_16x16x32_f16(*(const f16x8*)&AsB[lm][ca1],
                        *(const f16x8*)&Us[g * 16 + lm][ca1], a1, 0, 0, 0);
                a2 = __builtin_amdgcn_mfma_f32_16x16x32_f16(*(const f16x8*)&AsB[lm][ca2],
                        *(const f16x8*)&Us[g * 16 + lm][ca2], a2, 0, 0, 0);
                a3 = __builtin_amdgcn_mfma_f32_16x16x32_f16(*(const f16x8*)&AsB[lm][ca3],
                        *(const f16x8*)&Us[g * 16 + lm][ca3], a3, 0, 0, 0);
            }
            f32x4 acc = (a0 + a1) + (a2 + a3);
            if (lg < 2) {
#pragma unroll
                for (int i = 0; i < 4; ++i) zs[g][lg * 4 + i][lm] = acc[i];
            }
        }
        __syncthreads();
        // ---- tail B ----
        if (t + 1 < NTIME) {
            wait_vm0(&prB_a, &prB_b, &puA[0], &puA[1], &puA[2], &puA[3]);
            // pxA(t+1) was issued in tail A; now guaranteed -> convert
            if (lg < 2) {
#pragma unroll
                for (int i = 0; i < 4; ++i) pxA[i] = f16bits_to_f32(puA[i]);
            }
            if (!(chunk_clean(prB_a) && chunk_clean(prB_b))) {   // fallback poll
                const f16* src = hsl + (size_t)(t % 3) * HSZ
                               + (size_t)(r0A + prow) * NUNITS;
                for (int spin = 0; spin < 65536; ++spin) {
                    load2x16_sys(src + pc0 * 8, src + (pc0 + 32) * 8, &prB_a, &prB_b);
                    if (chunk_clean(prB_a) && chunk_clean(prB_b)) break;
                }
            }
            *(f32x4*)&AsA[prow][(pc0 ^ (prow & 7)) * 8]        = prB_a;
            *(f32x4*)&AsA[prow][((pc0 + 32) ^ (prow & 7)) * 8] = prB_b;
            if (tid < 16) {   // poison A-rows of slot (t+2)%3
                f16* ps = hsl + (size_t)((t + 2) % 3) * HSZ
                              + (size_t)(r0A + (tid >> 1)) * NUNITS + u0 + (tid & 1) * 8;
                store_16B_sys(ps, pz);
            }
        }
        // state B
        if (tid < 128) {
            const float zi = zs[0][srow][suu];
            const float zf = zs[1][srow][suu];
            const float zg_ = zs[2][srow][suu];
            const float zo = zs[3][srow][suu];
            const float iv = sigmoidf_(zi);
            const float fv = sigmoidf_(zf);
            const float gv = tanhf_(zg_);
            const float ov = sigmoidf_(zo);
            c_regB = fv * c_regB + iv * gv;
            const float hn = ov * tanhf_(c_regB);
            if (t == NTIME - 1) {
                out[gidxB]          = hn;
                out[65536 + gidxB]  = hn;
                out[131072 + gidxB] = c_regB;
            } else {
                union { f16 h; unsigned short u; } cv; cv.h = (f16)hn;
                store_u16_sys(hsl + (size_t)(t % 3) * HSZ + gidxB, cv.u);
            }
        }
        // async xz prefetch pxB(t+1) — guaranteed by phase A(t+1) tail's wait
        if (t + 1 < NTIME && lg < 2) {
            issue_px(xz + ((size_t)(t + 1) * NBATCH + r0B + lg * 4) * NGATE
                        + g * NUNITS + u0 + lm, &puB[0], &puB[1], &puB[2], &puB[3]);
        }
        __syncthreads();
    }
}

extern "C" void kernel_launch(void* const* d_in, const int* in_sizes, int n_in,
                              void* d_out, int out_size, void* d_ws, size_t ws_size,
                              hipStream_t stream) {
    const float* x    = (const float*)d_in[0];
    const float* W    = (const float*)d_in[1];
    const float* U    = (const float*)d_in[2];
    const float* bias = (const float*)d_in[3];
    float* out = (float*)d_out;
    char* ws = (char*)d_ws;

    size_t off = 0;
    f16* Wt = (f16*)(ws + off); off += (size_t)NGATE * NKIN * 2;
    f16* Ut = (f16*)(ws + off); off += (size_t)NGATE * NUNITS * 2;
    f16* xz = (f16*)(ws + off); off += (size_t)NTIME * NBATCH * NGATE * 2;  // [t][b][g]
    f16* hsl = (f16*)(ws + off); off += (size_t)3 * HSZ * 2;                // 3 h slots
    if (ws_size < off) return;

    k_poison<<<dim3(96), 256, 0, stream>>>(hsl);
    k_transpose<<<dim3(32, 8), 256, 0, stream>>>(W, Wt);
    k_transpose<<<dim3(32, 8), 256, 0, stream>>>(U, Ut);
    k_proj<<<dim3(16, 128), 256, 0, stream>>>(x, Wt, bias, xz);
    k_lstm<<<dim3(256), 256, 0, stream>>>(xz, Ut, hsl, out);
}